// Round 3
// baseline (186.412 us; speedup 1.0000x reference)
//
#include <hip/hip_runtime.h>
#include <hip/hip_bf16.h>

typedef __attribute__((ext_vector_type(4))) float f32x4;
typedef __attribute__((ext_vector_type(8))) short bf16x8;
typedef __attribute__((ext_vector_type(4))) unsigned short u16x4;
typedef __attribute__((ext_vector_type(8))) unsigned short u16x8;

__device__ __forceinline__ unsigned short f2bf(float f) {
    unsigned int u = __builtin_bit_cast(unsigned int, f);
    u += 0x7fffu + ((u >> 16) & 1u);   // RNE; inputs finite
    return (unsigned short)(u >> 16);
}

// swizzle in ushort units: rows are 64 ushorts (128 B); XOR bits 3..5 with row&7
#define SWZ(i) ((i) ^ ((((i) >> 6) & 7) << 3))

constexpr int BM = 64, BN = 128, BK = 64;

// Writes W^T in TILED+SWIZZLED form: dst is [ntile][rows/64] tiles of 8192
// ushorts; element (n,k) of W^T lives at tile(n>>7, k>>6), idx SWZ((n&127)*64+(k&63)).
// This is exactly the LDS image the GEMM expects, so B can be staged with
// global_load_lds (linear dest) and read with swizzled ds_read (rule #21).
__global__ void transpose_cvt(const float* __restrict__ src,
                              unsigned short* __restrict__ dst,
                              int rows, int cols) {
    int idx = blockIdx.x * 256 + threadIdx.x;     // idx = n*rows + k
    int n = idx / rows;
    int k = idx - n * rows;
    unsigned short v = f2bf(src[(size_t)k * cols + n]);
    int ntile = n >> 7, ktile = k >> 6;
    dst[((size_t)(ntile * (rows >> 6) + ktile)) * 8192 +
        SWZ((n & 127) * 64 + (k & 63))] = v;
}

// D = A(f32, MxK) @ B (bf16, tiled+swizzled [ntile][K/64][8192]) + epilogue
// EPI 0: D = tiled+swizzled bf16 (acc + epi)   [T = input@W1 + W2 -> big-GEMM B]
// EPI 1: D(f32) = acc + bias[col]              [C0 = x@W3 + b]
// EPI 2: D(f32) = acc + epi[row*lde+col]       [out = adj@T + C0]
template<int EPI>
__global__ __launch_bounds__(512, 4)
void gemm_k(const float* __restrict__ A, long lda,
            const unsigned short* __restrict__ Bt,
            int K,
            const float* __restrict__ epi, long lde,
            const float* __restrict__ bias,
            void* __restrict__ Dptr, long ldd) {
    __shared__ unsigned short sA[2][BM * BK];   // 8 KB per buf
    __shared__ unsigned short sB[2][BN * BK];   // 16 KB per buf  (total 48 KB)

    const int t = threadIdx.x;          // 0..511
    const int l = t & 63;
    const int w = t >> 6;               // wave 0..7
    const int wm = w >> 2;              // 0..1  (32-row slab)
    const int wn = w & 3;               // 0..3  (32-col slab)

    // XCD-bijective swizzle: all n-tiles of one m-panel on one XCD.
    int mt, nt;
    {
        int lin = blockIdx.y * gridDim.x + blockIdx.x;   // gridDim.y % 8 == 0
        int xcd = lin & 7;
        int slot = lin >> 3;
        int ppx = gridDim.y >> 3;
        mt = xcd * ppx + slot / gridDim.x;
        nt = slot % gridDim.x;
    }
    const long m0 = (long)mt * BM;
    const long n0 = (long)nt * BN;
    const int KT = K >> 6;
    const unsigned short* Bblk = Bt + (size_t)nt * KT * 8192;

    f32x4 acc[2][2];
    #pragma unroll
    for (int m = 0; m < 2; ++m)
        #pragma unroll
        for (int n = 0; n < 2; ++n)
            acc[m][n] = {0.f, 0.f, 0.f, 0.f};

    // two named A register stages (static naming — rule #20)
    f32x4 aX0, aX1, aY0, aY1;

    auto gll_B = [&](int kt, int buf) {
        const unsigned short* src = Bblk + (size_t)kt * 8192 + t * 8;
        #pragma unroll
        for (int r = 0; r < 2; ++r) {
            __builtin_amdgcn_global_load_lds(
                (const __attribute__((address_space(1))) void*)(src + r * 4096),
                (__attribute__((address_space(3))) void*)&sB[buf][r * 4096 + w * 512],
                16, 0, 0);
        }
    };

    // pinned-issue-order A load (inline asm so manual vmcnt counts are sound)
    auto load_A = [&](int kt, f32x4& a0, f32x4& a1) {
        const float* p0 = &A[(m0 + (t >> 4)) * lda + (long)kt * BK + ((t & 15) << 2)];
        const float* p1 = p0 + 32 * lda;
        asm volatile("global_load_dwordx4 %0, %2, off\n\t"
                     "global_load_dwordx4 %1, %3, off"
                     : "=&v"(a0), "=&v"(a1)
                     : "v"(p0), "v"(p1)
                     : "memory");
    };

    auto write_A = [&](int buf, const f32x4& a0, const f32x4& a1) {
        int e0 = t * 4;
        u16x4 w0 = {f2bf(a0[0]), f2bf(a0[1]), f2bf(a0[2]), f2bf(a0[3])};
        *reinterpret_cast<u16x4*>(&sA[buf][SWZ(e0)]) = w0;
        int e1 = 2048 + t * 4;
        u16x4 w1 = {f2bf(a1[0]), f2bf(a1[1]), f2bf(a1[2]), f2bf(a1[3])};
        *reinterpret_cast<u16x4*>(&sA[buf][SWZ(e1)]) = w1;
    };

    auto compute = [&](int buf) {
        #pragma unroll
        for (int kk = 0; kk < 2; ++kk) {
            bf16x8 af[2], bfr[2];
            const int kb = kk * 32 + ((l >> 4) << 3);
            #pragma unroll
            for (int m = 0; m < 2; ++m) {
                int row = wm * 32 + m * 16 + (l & 15);
                af[m] = *reinterpret_cast<const bf16x8*>(&sA[buf][SWZ(row * 64 + kb)]);
            }
            #pragma unroll
            for (int n = 0; n < 2; ++n) {
                int col = wn * 32 + n * 16 + (l & 15);
                bfr[n] = *reinterpret_cast<const bf16x8*>(&sB[buf][SWZ(col * 64 + kb)]);
            }
            __builtin_amdgcn_s_setprio(1);
            #pragma unroll
            for (int m = 0; m < 2; ++m)
                #pragma unroll
                for (int n = 0; n < 2; ++n)
                    acc[m][n] = __builtin_amdgcn_mfma_f32_16x16x32_bf16(
                        af[m], bfr[n], acc[m][n], 0, 0, 0);
            __builtin_amdgcn_s_setprio(0);
        }
    };

    // ---- prologue: outstanding order [B0 gll x2, A0 x2, A1 x2] ----
    gll_B(0, 0);
    load_A(0, aX0, aX1);
    load_A(1, aY0, aY1);
    asm volatile("s_waitcnt vmcnt(2)" ::: "memory");   // B(0)+A(0) done, A(1) flying
    __builtin_amdgcn_sched_barrier(0);
    write_A(0, aX0, aX1);
    asm volatile("s_waitcnt lgkmcnt(0)" ::: "memory");
    __builtin_amdgcn_s_barrier();
    __builtin_amdgcn_sched_barrier(0);

    const int nk = K >> 6;     // 128 or 8; main loop needs nk >= 4, even
    for (int p = 0; p + 2 < nk; p += 2) {
        // even phase: tile p (buf0). held aY=A(p+1); refill aX=A(p+2); B(p+1)->ldsB[1]
        gll_B(p + 1, 1);
        load_A(p + 2, aX0, aX1);
        compute(0);
        asm volatile("s_waitcnt vmcnt(4)" ::: "memory");   // A(p+1) landed
        __builtin_amdgcn_sched_barrier(0);
        write_A(1, aY0, aY1);
        asm volatile("s_waitcnt vmcnt(2) lgkmcnt(0)" ::: "memory"); // B(p+1) landed
        __builtin_amdgcn_s_barrier();
        __builtin_amdgcn_sched_barrier(0);

        // odd phase: tile p+1 (buf1). held aX=A(p+2); refill aY=A(p+3); B(p+2)->ldsB[0]
        gll_B(p + 2, 0);
        load_A(p + 3, aY0, aY1);
        compute(1);
        asm volatile("s_waitcnt vmcnt(4)" ::: "memory");
        __builtin_amdgcn_sched_barrier(0);
        write_A(0, aX0, aX1);
        asm volatile("s_waitcnt vmcnt(2) lgkmcnt(0)" ::: "memory");
        __builtin_amdgcn_s_barrier();
        __builtin_amdgcn_sched_barrier(0);
    }

    // peel phase nk-2 (buf0): held aY=A(nk-1)
    gll_B(nk - 1, 1);
    compute(0);
    asm volatile("s_waitcnt vmcnt(2)" ::: "memory");       // A(nk-1) landed
    __builtin_amdgcn_sched_barrier(0);
    write_A(1, aY0, aY1);
    asm volatile("s_waitcnt vmcnt(0) lgkmcnt(0)" ::: "memory");
    __builtin_amdgcn_s_barrier();
    __builtin_amdgcn_sched_barrier(0);

    // peel phase nk-1 (buf1)
    compute(1);

    // ---- epilogue ----
    const int jrow = (l >> 4) * 4;
    #pragma unroll
    for (int m = 0; m < 2; ++m) {
        const long row = m0 + wm * 32 + m * 16 + jrow;
        #pragma unroll
        for (int n = 0; n < 2; ++n) {
            const long col = n0 + wn * 32 + n * 16 + (l & 15);
            f32x4 v = acc[m][n];
            if constexpr (EPI == 0) {
                u16x4 o;
                #pragma unroll
                for (int j = 0; j < 4; ++j)
                    o[j] = f2bf(v[j] + epi[(row + j) * lde + col]);
                // tiled+swizzled bf16 store; row%4==0 so the 4 elems stay
                // contiguous after SWZ (bits 3..5 unaffected)
                int ntile = (int)(col >> 7), cl = (int)(col & 127);
                int ktile = (int)(row >> 6), kk = (int)(row & 63);
                *reinterpret_cast<u16x4*>(
                    &((unsigned short*)Dptr)[((size_t)(ntile * (int)ldd + ktile)) * 8192 +
                                             SWZ(cl * 64 + kk)]) = o;
            } else if constexpr (EPI == 1) {
                float b = bias[col];
                #pragma unroll
                for (int j = 0; j < 4; ++j)
                    ((float*)Dptr)[(row + j) * ldd + col] = v[j] + b;
            } else {
                #pragma unroll
                for (int j = 0; j < 4; ++j)
                    ((float*)Dptr)[(row + j) * ldd + col] =
                        v[j] + epi[(row + j) * lde + col];
            }
        }
    }
}

extern "C" void kernel_launch(void* const* d_in, const int* in_sizes, int n_in,
                              void* d_out, int out_size, void* d_ws, size_t ws_size,
                              hipStream_t stream) {
    const float* input  = (const float*)d_in[0];   // 8192 x 512
    const float* adj    = (const float*)d_in[1];   // 8192 x 8192
    const float* x      = (const float*)d_in[2];   // 8192 x 512
    const float* weight = (const float*)d_in[3];   // 9216 x 512
    const float* bias   = (const float*)d_in[4];   // 512

    const int N = 8192, IN_F = 512, NFEAT = 512, OUT_F = 512;
    float* out = (float*)d_out;

    // workspace layout (~25.7 MB)
    unsigned short* Tbt = (unsigned short*)d_ws;            // [4][128][8192] bf16 tiles
    unsigned short* W1t = Tbt + (size_t)OUT_F * N;          // [4][8][8192]
    unsigned short* W3t = W1t + (size_t)OUT_F * IN_F;       // [4][8][8192]
    float* C0 = (float*)(W3t + (size_t)OUT_F * NFEAT);      // [8192][512] f32

    transpose_cvt<<<dim3((IN_F * OUT_F) / 256), dim3(256), 0, stream>>>(
        weight, W1t, IN_F, OUT_F);
    transpose_cvt<<<dim3((NFEAT * OUT_F) / 256), dim3(256), 0, stream>>>(
        weight + (size_t)(IN_F + N) * OUT_F, W3t, NFEAT, OUT_F);

    dim3 grid(OUT_F / BN, N / BM);  // (4, 128) = 512 blocks, 3 blocks/CU by LDS

    // T = input @ W1 + W2  -> Tbt (tiled+swizzled bf16; ldd = K-tiles of big GEMM)
    gemm_k<0><<<grid, 512, 0, stream>>>(
        input, (long)IN_F, W1t, IN_F,
        weight + (size_t)IN_F * OUT_F, (long)OUT_F, nullptr,
        Tbt, (long)(N / 64));

    // C0 = x @ W3 + bias
    gemm_k<1><<<grid, 512, 0, stream>>>(
        x, (long)NFEAT, W3t, NFEAT,
        nullptr, 0, bias,
        C0, (long)OUT_F);

    // out = adj @ T + C0
    gemm_k<2><<<grid, 512, 0, stream>>>(
        adj, (long)N, Tbt, N,
        C0, (long)OUT_F, nullptr,
        out, (long)OUT_F);
}